// Round 6
// baseline (79.986 us; speedup 1.0000x reference)
//
#include <hip/hip_runtime.h>

typedef __attribute__((ext_vector_type(8))) short short8;
typedef __attribute__((ext_vector_type(4))) float f32x4;

// round-to-nearest-even f32 -> bf16 bits
__device__ __forceinline__ unsigned short f2b(float f) {
  unsigned int u = __float_as_uint(f);
  return (unsigned short)((u + 0x7FFFu + ((u >> 16) & 1u)) >> 16);
}
__device__ __forceinline__ unsigned pk2(float a, float b) {
  return (unsigned)f2b(a) | ((unsigned)f2b(b) << 16);
}

#define NBLK 768
#define NTILE 4096   // batch-pairs: 8192/2

// d_out is float*, holding Re(out) only:
// Re(out)[b, i*64+k] = sum_j cos(phase[j][i])*hr[b,j*64+k] - sin(phase[j][i])*hi[b,j*64+k]
//
// Persistent blocks: 768 blocks (3/CU), each grid-strides over ~5-6 tiles
// (tile = 2 batches). 8 waves; wave w: batch = w>>2, i-quarter = w&3 (M=16).
// psi fragments computed ONCE per block. Per tile, next tile's global loads
// are issued before the second barrier and stay in flight (raw s_barrier +
// lgkmcnt(0) only — no vmcnt drain).
__global__ __launch_bounds__(512, 4) void tnn_kernel(
    const float* __restrict__ phase,
    const float* __restrict__ hr, const float* __restrict__ hi,
    float* __restrict__ out) {
  __shared__ alignas(16) char lds[32768];
  const int tid = threadIdx.x;
  const int lane = tid & 63;
  const int w8 = tid >> 6;
  const int bb = w8 >> 2;           // batch within tile
  const int ibase = (w8 & 3) * 16;  // i-quarter

  // ---- psi A-fragments once per block: Are = cos, Ans = -sin ----
  // A-frag (16x16x32): row m = lane&15, k = (lane>>4)*8 + q.
  short8 Are[2], Ans[2];
#pragma unroll
  for (int ks = 0; ks < 2; ++ks) {
    const int i = ibase + (lane & 15);
    const int j0 = ks * 32 + (lane >> 4) * 8;
#pragma unroll
    for (int q = 0; q < 8; ++q) {
      float p = phase[(j0 + q) * 64 + i];
      float s, c;
      __sincosf(p, &s, &c);
      Are[ks][q] = (short)f2b(c);
      Ans[ks][q] = (short)f2b(-s);
    }
  }

  const size_t soff = (size_t)(w8 * 8) * 64 + lane;  // j-octet + k within batch
  const int wbyte = lane * 128 + ((w8 * 16) ^ ((lane & 7) << 4));  // swizzled LDS row k=lane

  float v[2][2][8];  // [batch][re/im][q] — all indices compile-time (rule #20)
  int tile = blockIdx.x;

  // prologue: issue loads for first tile
#pragma unroll
  for (int b = 0; b < 2; ++b) {
    const float* p0 = hr + (size_t)(2 * tile + b) * 4096 + soff;
    const float* p1 = hi + (size_t)(2 * tile + b) * 4096 + soff;
#pragma unroll
    for (int q = 0; q < 8; ++q) v[b][0][q] = p0[(size_t)q * 64];
#pragma unroll
    for (int q = 0; q < 8; ++q) v[b][1][q] = p1[(size_t)q * 64];
  }

  while (tile < NTILE) {
    const int tnext = (tile + NBLK < NTILE) ? (tile + NBLK) : tile;  // clamp: harmless reload

    // ---- cvt + pack current tile (compiler auto-waits vmcnt on first use) ----
    uint4 pka[2], pkb[2];
#pragma unroll
    for (int b = 0; b < 2; ++b) {
      pka[b].x = pk2(v[b][0][0], v[b][0][1]);
      pka[b].y = pk2(v[b][0][2], v[b][0][3]);
      pka[b].z = pk2(v[b][0][4], v[b][0][5]);
      pka[b].w = pk2(v[b][0][6], v[b][0][7]);
      pkb[b].x = pk2(v[b][1][0], v[b][1][1]);
      pkb[b].y = pk2(v[b][1][2], v[b][1][3]);
      pkb[b].z = pk2(v[b][1][4], v[b][1][5]);
      pkb[b].w = pk2(v[b][1][6], v[b][1][7]);
    }

    // barrier 1: all waves' LDS reads of previous tile complete -> safe to overwrite
    asm volatile("s_waitcnt lgkmcnt(0)" ::: "memory");
    __builtin_amdgcn_s_barrier();

    // ---- LDS write (XOR-swizzled [k=64][j=64] bf16 rows, per batch/re-im) ----
#pragma unroll
    for (int b = 0; b < 2; ++b) {
      *reinterpret_cast<uint4*>(lds + (b * 2 + 0) * 8192 + wbyte) = pka[b];
      *reinterpret_cast<uint4*>(lds + (b * 2 + 1) * 8192 + wbyte) = pkb[b];
    }

    // ---- issue next tile's loads: stay in flight across the barrier ----
#pragma unroll
    for (int b = 0; b < 2; ++b) {
      const float* p0 = hr + (size_t)(2 * tnext + b) * 4096 + soff;
      const float* p1 = hi + (size_t)(2 * tnext + b) * 4096 + soff;
#pragma unroll
      for (int q = 0; q < 8; ++q) v[b][0][q] = p0[(size_t)q * 64];
#pragma unroll
      for (int q = 0; q < 8; ++q) v[b][1][q] = p1[(size_t)q * 64];
    }

    // barrier 2: own ds_writes drained (lgkmcnt only — vmcnt prefetch stays in flight)
    asm volatile("s_waitcnt lgkmcnt(0)" ::: "memory");
    __builtin_amdgcn_s_barrier();

    // ---- MFMA (real part only) ----
    f32x4 acc[4] = {};
    const char* Xre = lds + (bb * 2 + 0) * 8192;
    const char* Xim = lds + (bb * 2 + 1) * 8192;
#pragma unroll
    for (int kt = 0; kt < 4; ++kt) {
      const int row = kt * 16 + (lane & 15);
#pragma unroll
      for (int ks = 0; ks < 2; ++ks) {
        const int cbyte = ks * 64 + (lane >> 4) * 16;
        const int byte = row * 128 + (cbyte ^ ((row & 7) << 4));
        uint4 xr4 = *reinterpret_cast<const uint4*>(Xre + byte);
        uint4 xi4 = *reinterpret_cast<const uint4*>(Xim + byte);
        short8 xr = __builtin_bit_cast(short8, xr4);
        short8 xi = __builtin_bit_cast(short8, xi4);
        acc[kt] = __builtin_amdgcn_mfma_f32_16x16x32_bf16(Are[ks], xr, acc[kt], 0, 0, 0);
        acc[kt] = __builtin_amdgcn_mfma_f32_16x16x32_bf16(Ans[ks], xi, acc[kt], 0, 0, 0);
      }
    }

    // ---- epilogue: scalar f32 stores (real part) ----
    // C/D (16x16x32): col = lane&15, row = (lane>>4)*4 + r.
    const size_t obase = (size_t)(2 * tile + bb) * 4096;
#pragma unroll
    for (int kt = 0; kt < 4; ++kt) {
#pragma unroll
      for (int r = 0; r < 4; ++r) {
        int i = ibase + (lane >> 4) * 4 + r;
        int kc = kt * 16 + (lane & 15);
        out[obase + (size_t)i * 64 + kc] = acc[kt][r];
      }
    }

    tile += NBLK;
  }
}

extern "C" void kernel_launch(void* const* d_in, const int* in_sizes, int n_in,
                              void* d_out, int out_size, void* d_ws, size_t ws_size,
                              hipStream_t stream) {
  const float* phase = (const float*)d_in[0];
  const float* hr = (const float*)d_in[1];
  const float* hi = (const float*)d_in[2];
  float* out = (float*)d_out;

  tnn_kernel<<<NBLK, 512, 0, stream>>>(phase, hr, hi, out);
}

// Round 7
// 79.027 us; speedup vs baseline: 1.0121x; 1.0121x over previous
//
#include <hip/hip_runtime.h>

typedef __attribute__((ext_vector_type(8))) short short8;
typedef __attribute__((ext_vector_type(4))) float f32x4;

// round-to-nearest-even f32 -> bf16 bits
__device__ __forceinline__ unsigned short f2b(float f) {
  unsigned int u = __float_as_uint(f);
  return (unsigned short)((u + 0x7FFFu + ((u >> 16) & 1u)) >> 16);
}
__device__ __forceinline__ unsigned pk2(float a, float b) {
  return (unsigned)f2b(a) | ((unsigned)f2b(b) << 16);
}

// d_out is float*, holding Re(out) only:
// Re(out)[b, i*64+k] = sum_j cos(phase[j][i])*hr[b,j*64+k] - sin(phase[j][i])*hi[b,j*64+k]
//
// Block: 512 threads = 8 waves, 2 batches, 32KB LDS (R4 structure).
// Staging now uses float4 global loads (16B/lane): wave w stages plane
// p = w&3 (batch = p>>1, re/im = p&1), j-half jh = w>>2. Lane: jo = lane&3
// (j-octet), kq = lane>>2 (k-quad). Each thread: 8 float4 loads (8 j-rows x
// 4 k), register transpose, 4 ds_write_b128 into XOR-swizzled [k][j] tile.
// Compute waves: wave w: batch = w>>2, i-quarter = w&3 (M=16).
__global__ __launch_bounds__(512, 4) void tnn_kernel(
    const float* __restrict__ phase,
    const float* __restrict__ hr, const float* __restrict__ hi,
    float* __restrict__ out) {
  __shared__ alignas(16) char lds[32768];
  const int tid = threadIdx.x;
  const int lane = tid & 63;
  const int w8 = tid >> 6;
  const int b0 = blockIdx.x * 2;

  const int bb = w8 >> 2;           // batch this wave computes
  const int ibase = (w8 & 3) * 16;  // i-quarter (M=16)

  // ---- stage X into LDS: float4 loads + in-register 8jx4k transpose ----
  {
    const int p = w8 & 3;           // plane: (batch<<1)|comp
    const int jh = w8 >> 2;         // j-half
    const int jo = lane & 3;        // j-octet within half
    const int kq = lane >> 2;       // k-quad
    const float* src = (p & 1 ? hi : hr) + (size_t)(b0 + (p >> 1)) * 4096;
    const int j0 = jh * 32 + jo * 8;
    const f32x4* sp = reinterpret_cast<const f32x4*>(src + (size_t)j0 * 64 + kq * 4);
    f32x4 v[8];
#pragma unroll
    for (int q = 0; q < 8; ++q) v[q] = sp[q * 16];  // next j-row = 64 floats = 16 float4
    char* plane = lds + p * 8192;
    const int colb = jh * 64 + jo * 16;             // byte col = 2*j0
#pragma unroll
    for (int kk = 0; kk < 4; ++kk) {
      const int row = kq * 4 + kk;                  // k
      uint4 wv;
      wv.x = pk2(v[0][kk], v[1][kk]);
      wv.y = pk2(v[2][kk], v[3][kk]);
      wv.z = pk2(v[4][kk], v[5][kk]);
      wv.w = pk2(v[6][kk], v[7][kk]);
      *reinterpret_cast<uint4*>(plane + row * 128 + (colb ^ ((row & 7) << 4))) = wv;
    }
  }

  // ---- psi A-fragments in-register: Are = cos(phase[j][i]), Ans = -sin ----
  // A-frag (16x16x32): row m = lane&15, k = (lane>>4)*8 + q.
  short8 Are[2], Ans[2];
#pragma unroll
  for (int ks = 0; ks < 2; ++ks) {
    const int i = ibase + (lane & 15);
    const int j0 = ks * 32 + (lane >> 4) * 8;
#pragma unroll
    for (int q = 0; q < 8; ++q) {
      float pph = phase[(j0 + q) * 64 + i];
      float s, c;
      __sincosf(pph, &s, &c);
      Are[ks][q] = (short)f2b(c);
      Ans[ks][q] = (short)f2b(-s);
    }
  }

  __syncthreads();

  // ---- MFMA compute (real part only) ----
  f32x4 acc[4] = {};
  const char* Xre = lds + (bb * 2 + 0) * 8192;
  const char* Xim = lds + (bb * 2 + 1) * 8192;

#pragma unroll
  for (int kt = 0; kt < 4; ++kt) {
    const int row = kt * 16 + (lane & 15);
#pragma unroll
    for (int ks = 0; ks < 2; ++ks) {
      const int cbyte = ks * 64 + (lane >> 4) * 16;
      const int byte = row * 128 + (cbyte ^ ((row & 7) << 4));
      uint4 xr4 = *reinterpret_cast<const uint4*>(Xre + byte);
      uint4 xi4 = *reinterpret_cast<const uint4*>(Xim + byte);
      short8 xr = __builtin_bit_cast(short8, xr4);
      short8 xi = __builtin_bit_cast(short8, xi4);
      acc[kt] = __builtin_amdgcn_mfma_f32_16x16x32_bf16(Are[ks], xr, acc[kt], 0, 0, 0);
      acc[kt] = __builtin_amdgcn_mfma_f32_16x16x32_bf16(Ans[ks], xi, acc[kt], 0, 0, 0);
    }
  }

  // ---- epilogue: scalar f32 stores (real part) ----
  // C/D (16x16x32): col = lane&15, row = (lane>>4)*4 + r.
  const size_t obase = (size_t)(b0 + bb) * 4096;
#pragma unroll
  for (int kt = 0; kt < 4; ++kt) {
#pragma unroll
    for (int r = 0; r < 4; ++r) {
      int i = ibase + (lane >> 4) * 4 + r;
      int kc = kt * 16 + (lane & 15);
      out[obase + (size_t)i * 64 + kc] = acc[kt][r];
    }
  }
}

extern "C" void kernel_launch(void* const* d_in, const int* in_sizes, int n_in,
                              void* d_out, int out_size, void* d_ws, size_t ws_size,
                              hipStream_t stream) {
  const float* phase = (const float*)d_in[0];
  const float* hr = (const float*)d_in[1];
  const float* hi = (const float*)d_in[2];
  float* out = (float*)d_out;

  tnn_kernel<<<4096, 512, 0, stream>>>(phase, hr, hi, out);
}